// Round 8
// baseline (473.482 us; speedup 1.0000x reference)
//
#include <hip/hip_runtime.h>

typedef float        f32x4  __attribute__((ext_vector_type(4)));
typedef __bf16       bf16x8 __attribute__((ext_vector_type(8)));
typedef unsigned int u32x4  __attribute__((ext_vector_type(4)));

#define NN   8192
#define IND  256
#define OUTD 128
#define NB   144     // n: 0..127 = B cols, 128 = denominator, 129..143 = 0
#define NT   9       // n-tiles of 16
#define KSPLIT 8     // 2 blockIdx.y x 4 waves

__device__ __forceinline__ bf16x8 cvt2(f32x4 a, f32x4 b) {
  bf16x8 r;
  r[0]=(__bf16)a[0]; r[1]=(__bf16)a[1]; r[2]=(__bf16)a[2]; r[3]=(__bf16)a[3];
  r[4]=(__bf16)b[0]; r[5]=(__bf16)b[1]; r[6]=(__bf16)b[2]; r[7]=(__bf16)b[3];
  return r;
}

// bits[0..7] of byte -> bf16x8 {0.0,1.0}: pair j from bits 2j,2j+1 via
// sel in {0,1,0x10000,0x10001}; sel*0x3F80 packs two bf16 in one dword.
__device__ __forceinline__ bf16x8 unpack8(unsigned int byte) {
  u32x4 d;
#pragma unroll
  for (int j = 0; j < 4; ++j) {
    const unsigned int t   = (byte >> (2 * j)) & 3u;
    const unsigned int sel = (t & 1u) | ((t & 2u) << 15);
    d[j] = sel * 0x3F80u;
  }
  return __builtin_bit_cast(bf16x8, d);
}

// K0: bit-pack adjacency. Wave W packs row W (8192 floats -> 128 u64).
// ballot bit l corresponds to k = base + l (lane l tests element base+l).
__global__ __launch_bounds__(256) void k0_bits(const float* __restrict__ A,
                                               unsigned long long* __restrict__ Abits) {
  const int lane = threadIdx.x & 63;
  const int W    = blockIdx.x * 4 + (threadIdx.x >> 6);  // row 0..8191
  const float* ap = A + (size_t)W * NN;
  unsigned long long* op = Abits + (size_t)W * 128;
#pragma unroll 4
  for (int i = 0; i < 32; ++i) {
    const float f0 = __builtin_nontemporal_load(ap + i * 256 + lane);
    const float f1 = __builtin_nontemporal_load(ap + i * 256 + 64 + lane);
    const float f2 = __builtin_nontemporal_load(ap + i * 256 + 128 + lane);
    const float f3 = __builtin_nontemporal_load(ap + i * 256 + 192 + lane);
    const unsigned long long b0 = __ballot(f0 > 0.5f);
    const unsigned long long b1 = __ballot(f1 > 0.5f);
    const unsigned long long b2 = __ballot(f2 > 0.5f);
    const unsigned long long b3 = __ballot(f3 > 0.5f);
    if (lane == 0) {
      ulonglong2 v01; v01.x = b0; v01.y = b1;
      ulonglong2 v23; v23.x = b2; v23.y = b3;
      *(ulonglong2*)(op + i * 4)     = v01;
      *(ulonglong2*)(op + i * 4 + 2) = v23;
    }
  }
}

// K1: Wh = X @ W^T  [8192,128] fp32; e[j] = relu(Wh[j]) . a_w
__global__ __launch_bounds__(128) void k1_wh_e(const float* __restrict__ X,
                                               const float* __restrict__ W,
                                               const float* __restrict__ aw,
                                               float* __restrict__ Wh,
                                               float* __restrict__ ev) {
  const int lane = threadIdx.x & 63;
  const int wave = threadIdx.x >> 6;
  const int nlo  = lane & 15;
  const int quad = lane >> 4;
  const int rowBase = blockIdx.x * 32 + wave * 16;

  const float* xp = X + (size_t)(rowBase + nlo) * IND + quad * 8;
  f32x4 acc[8];
#pragma unroll
  for (int nt = 0; nt < 8; ++nt) acc[nt] = f32x4{0.f, 0.f, 0.f, 0.f};

#pragma unroll
  for (int kb = 0; kb < IND; kb += 32) {
    f32x4 a0 = *(const f32x4*)(xp + kb);
    f32x4 a1 = *(const f32x4*)(xp + kb + 4);
    bf16x8 af = cvt2(a0, a1);
#pragma unroll
    for (int nt = 0; nt < 8; ++nt) {
      const float* wp = W + (size_t)(nt * 16 + nlo) * IND + kb + quad * 8;
      f32x4 b0 = *(const f32x4*)wp;
      f32x4 b1 = *(const f32x4*)(wp + 4);
      acc[nt] = __builtin_amdgcn_mfma_f32_16x16x32_bf16(af, cvt2(b0, b1), acc[nt], 0, 0, 0);
    }
  }
  float p0 = 0.f, p1 = 0.f, p2 = 0.f, p3 = 0.f;
#pragma unroll
  for (int nt = 0; nt < 8; ++nt) {
    const int col = nt * 16 + nlo;
    const float awc = aw[col];
    const int r0 = rowBase + quad * 4;
    float v0 = acc[nt][0], v1 = acc[nt][1], v2 = acc[nt][2], v3 = acc[nt][3];
    Wh[(size_t)(r0 + 0) * OUTD + col] = v0;
    Wh[(size_t)(r0 + 1) * OUTD + col] = v1;
    Wh[(size_t)(r0 + 2) * OUTD + col] = v2;
    Wh[(size_t)(r0 + 3) * OUTD + col] = v3;
    p0 += fmaxf(v0, 0.f) * awc;
    p1 += fmaxf(v1, 0.f) * awc;
    p2 += fmaxf(v2, 0.f) * awc;
    p3 += fmaxf(v3, 0.f) * awc;
  }
#pragma unroll
  for (int off = 8; off; off >>= 1) {
    p0 += __shfl_xor(p0, off, 64);
    p1 += __shfl_xor(p1, off, 64);
    p2 += __shfl_xor(p2, off, 64);
    p3 += __shfl_xor(p3, off, 64);
  }
  if (nlo == 0) {
    const int r0 = rowBase + quad * 4;
    ev[r0 + 0] = p0; ev[r0 + 1] = p1; ev[r0 + 2] = p2; ev[r0 + 3] = p3;
  }
}

// K2: pack B into MFMA B-fragment-linear layout.
//   Bp[((T*NT+u)*64 + lane)*8 + j] = B[k = 32T + (lane>>4)*8 + j][n = 16u + (lane&15)]
// B[k][n] = exp(e_k)*Wh[k][n] (n<128), exp(e_k) (n==128), 0 (n>128).
__global__ __launch_bounds__(64) void k2_pack(const float* __restrict__ Wh,
                                              const float* __restrict__ ev,
                                              __bf16* __restrict__ Bp) {
  const int T = blockIdx.x, u = blockIdx.y;
  const int lane = threadIdx.x;
  const int nlo  = lane & 15;
  const int kbase = T * 32 + (lane >> 4) * 8;
  bf16x8 o;
  if (u < 8) {
#pragma unroll
    for (int j = 0; j < 8; ++j) {
      const float wk = expf(ev[kbase + j]);
      o[j] = (__bf16)(wk * Wh[(size_t)(kbase + j) * OUTD + u * 16 + nlo]);
    }
  } else {
#pragma unroll
    for (int j = 0; j < 8; ++j)
      o[j] = (nlo == 0) ? (__bf16)expf(ev[kbase + j]) : (__bf16)0.f;
  }
  *(bf16x8*)(Bp + ((size_t)(T * NT + u) * 64 + lane) * 8) = o;
}

// K3a: part[slice][m][NB] = Adj @ B, adjacency from packed bits.
// Grid (256, 2) x 256. Wave = 32 m-rows x 1024 k (slice = by*4 + wave).
// No LDS, no barriers, no HBM in the loop: A-bits from L1 (32 B/lane-iter
// broadcast), B frags register-direct from the L2-resident fragment-linear Bp.
__global__ __launch_bounds__(256, 2) void k3_partial(const unsigned int* __restrict__ Abits,
                                                     const __bf16* __restrict__ Bp,
                                                     float* __restrict__ part) {
  const int lane = threadIdx.x & 63;
  const int wave = threadIdx.x >> 6;
  const int nlo  = lane & 15;
  const int quad = lane >> 4;
  const int mBase = blockIdx.x * 32;
  const int slice = blockIdx.y * 4 + wave;   // 0..7
  const int kt0   = slice * 32;              // first of 32 ktiles (32 k each)

  const unsigned int* arow0 = Abits + (size_t)(mBase + nlo) * 256 + kt0;
  const unsigned int* arow1 = Abits + (size_t)(mBase + 16 + nlo) * 256 + kt0;
  const __bf16* bq = Bp + (size_t)kt0 * NT * 512 + (size_t)lane * 8;

  f32x4 acc[2][NT];
#pragma unroll
  for (int g = 0; g < 2; ++g)
#pragma unroll
    for (int t = 0; t < NT; ++t) acc[g][t] = f32x4{0.f, 0.f, 0.f, 0.f};

#pragma unroll
  for (int c = 0; c < 32; ++c) {
    bf16x8 bf[NT];
#pragma unroll
    for (int t = 0; t < NT; ++t)
      bf[t] = *(const bf16x8*)(bq + ((size_t)c * NT + t) * 512);
    const unsigned int w0 = arow0[c];
    const unsigned int w1 = arow1[c];
    const bf16x8 a0 = unpack8(w0 >> (quad * 8));
    const bf16x8 a1 = unpack8(w1 >> (quad * 8));
#pragma unroll
    for (int t = 0; t < NT; ++t) {
      acc[0][t] = __builtin_amdgcn_mfma_f32_16x16x32_bf16(a0, bf[t], acc[0][t], 0, 0, 0);
      acc[1][t] = __builtin_amdgcn_mfma_f32_16x16x32_bf16(a1, bf[t], acc[1][t], 0, 0, 0);
    }
  }

  // D: row = quad*4+rg -> m offset, col = lane&15 -> n offset (tile t)
#pragma unroll
  for (int g = 0; g < 2; ++g)
#pragma unroll
    for (int t = 0; t < NT; ++t)
#pragma unroll
      for (int rg = 0; rg < 4; ++rg)
        part[((size_t)slice * NN + mBase + g * 16 + quad * 4 + rg) * NB + t * 16 + nlo] =
            acc[g][t][rg];
}

// K3b: out[m][n] = relu( sum_s part[s][m][n] / sum_s part[s][m][128] )
__global__ __launch_bounds__(256) void k3_reduce(const float* __restrict__ part,
                                                 float* __restrict__ out) {
  const int n = threadIdx.x & 127;
  const int m = blockIdx.x * 2 + (threadIdx.x >> 7);
  float num = 0.f, den = 0.f;
#pragma unroll
  for (int s = 0; s < KSPLIT; ++s) {
    const float* pr = part + ((size_t)s * NN + m) * NB;
    num += pr[n];
    den += pr[128];
  }
  out[(size_t)m * OUTD + n] = fmaxf(num / den, 0.f);
}

extern "C" void kernel_launch(void* const* d_in, const int* in_sizes, int n_in,
                              void* d_out, int out_size, void* d_ws, size_t ws_size,
                              hipStream_t stream) {
  const float* X  = (const float*)d_in[0];
  const float* A  = (const float*)d_in[1];
  const float* W  = (const float*)d_in[2];
  const float* aw = (const float*)d_in[3];
  float* out = (float*)d_out;

  char* ws = (char*)d_ws;
  float*              Wh    = (float*)ws;                 // 4 MiB
  float*              ev    = (float*)(ws + 4194304);     // 32 KiB
  __bf16*             Bp    = (__bf16*)(ws + 4227072);    // 2.25 MiB
  unsigned long long* Abits = (unsigned long long*)(ws + 8388608);   // 8 MiB
  float*              part  = (float*)(ws + 16777216);    // 8*8192*144*4 = 37.75 MiB

  k0_bits<<<2048, 256, 0, stream>>>(A, Abits);
  k1_wh_e<<<256, 128, 0, stream>>>(X, W, aw, Wh, ev);
  k2_pack<<<dim3(256, NT), 64, 0, stream>>>(Wh, ev, Bp);
  k3_partial<<<dim3(256, 2), 256, 0, stream>>>((const unsigned int*)Abits, Bp, part);
  k3_reduce<<<4096, 256, 0, stream>>>(part, out);
}